// Round 7
// baseline (257.838 us; speedup 1.0000x reference)
//
#include <hip/hip_runtime.h>
#include <hip/hip_fp16.h>
#include <math.h>

// ---------------------------------------------------------------------------
// GCN. CSR build = bucketed counting sort, LDS atomics only (no global
// atomics: device-scope atomic-returns run memory-side at ~23 Gops/s on
// multi-XCD CDNA4 — measured R3/R4 — so they are banned here).
// Aggregation: atomic-free gather; t stored fp16 (halves gather bytes);
// 4 lane-groups x half4 loads, no inner-loop shuffles.
// ---------------------------------------------------------------------------

#define TPB    256
#define EBLKS  256          // pass-1 edge blocks (256 -> all CUs busy)
#define BSH    9            // 512 nodes per bucket
#define BNODES (1 << BSH)

// P1a: OFS[c*EBLKS + b] = #edges of bucket c in block b's chunk
__global__ __launch_bounds__(TPB)
void k_p1hist(const int* __restrict__ dst, int* __restrict__ OFS,
              int E, int CH, int NBC) {
    __shared__ int h[512];
    int tid = threadIdx.x, b = blockIdx.x;
    for (int i = tid; i < NBC; i += TPB) h[i] = 0;
    __syncthreads();
    int beg = b * CH, end = min(E, beg + CH);
    if (beg < end) {
        int nfull = (end - beg) & ~3;
        for (int i = beg + tid * 4; i < beg + nfull; i += TPB * 4) {
            int4 d = *(const int4*)&dst[i];
            atomicAdd(&h[d.x >> BSH], 1);
            atomicAdd(&h[d.y >> BSH], 1);
            atomicAdd(&h[d.z >> BSH], 1);
            atomicAdd(&h[d.w >> BSH], 1);
        }
        if (tid < (end - beg) - nfull)
            atomicAdd(&h[dst[beg + nfull + tid] >> BSH], 1);
    }
    __syncthreads();
    for (int c = tid; c < NBC; c += TPB) OFS[c * EBLKS + b] = h[c];
}

// Hierarchical exclusive scan of OFS[0..total)
__global__ __launch_bounds__(TPB)
void k_scanA(const int* __restrict__ OFS, int* __restrict__ bsum, int total) {
    __shared__ int s[TPB];
    int tid = threadIdx.x;
    int i0  = blockIdx.x * 1024 + tid * 4;
    int t = 0;
#pragma unroll
    for (int k = 0; k < 4; ++k) {
        int i = i0 + k;
        t += (i < total) ? OFS[i] : 0;
    }
    s[tid] = t;
    __syncthreads();
    for (int off = TPB / 2; off > 0; off >>= 1) {
        if (tid < off) s[tid] += s[tid + off];
        __syncthreads();
    }
    if (tid == 0) bsum[blockIdx.x] = s[0];
}

__global__ __launch_bounds__(TPB)
void k_scanB(int* bsum, int* OFS, int NBLK, int total, int E) {
    __shared__ int s[TPB];
    int tid = threadIdx.x;
    int v = (tid < NBLK) ? bsum[tid] : 0;
    s[tid] = v;
    __syncthreads();
    for (int off = 1; off < TPB; off <<= 1) {
        int x = (tid >= off) ? s[tid - off] : 0;
        __syncthreads();
        s[tid] += x;
        __syncthreads();
    }
    if (tid < NBLK) bsum[tid] = s[tid] - v;   // exclusive
    if (tid == 0) OFS[total] = E;             // sentinel
}

__global__ __launch_bounds__(TPB)
void k_scanC(int* __restrict__ OFS, const int* __restrict__ bsum, int total) {
    __shared__ int s[TPB];
    int tid = threadIdx.x;
    int i0  = blockIdx.x * 1024 + tid * 4;
    int v[4];
#pragma unroll
    for (int k = 0; k < 4; ++k) {
        int i = i0 + k;
        v[k] = (i < total) ? OFS[i] : 0;
    }
    int tsum = v[0] + v[1] + v[2] + v[3];
    s[tid] = tsum;
    __syncthreads();
    for (int off = 1; off < TPB; off <<= 1) {
        int x = (tid >= off) ? s[tid - off] : 0;
        __syncthreads();
        s[tid] += x;
        __syncthreads();
    }
    int base = bsum[blockIdx.x] + (s[tid] - tsum);
#pragma unroll
    for (int k = 0; k < 4; ++k) {
        int i = i0 + k;
        if (i < total) {
            OFS[i] = base;
            base += v[k];
        }
    }
}

// P1c: scatter (src,dst) into bucket-contiguous ebuf via LDS cursors
__global__ __launch_bounds__(TPB)
void k_p1scatter(const int* __restrict__ src, const int* __restrict__ dst,
                 const int* __restrict__ OFS, int2* __restrict__ ebuf,
                 int E, int CH, int NBC) {
    __shared__ int cur[512];
    int tid = threadIdx.x, b = blockIdx.x;
    for (int c = tid; c < NBC; c += TPB) cur[c] = OFS[c * EBLKS + b];
    __syncthreads();
    int beg = b * CH, end = min(E, beg + CH);
    if (beg >= end) return;
    int nfull = (end - beg) & ~3;
    for (int i = beg + tid * 4; i < beg + nfull; i += TPB * 4) {
        int4 s4 = *(const int4*)&src[i];
        int4 d4 = *(const int4*)&dst[i];
        int p0 = atomicAdd(&cur[d4.x >> BSH], 1);
        int p1 = atomicAdd(&cur[d4.y >> BSH], 1);
        int p2 = atomicAdd(&cur[d4.z >> BSH], 1);
        int p3 = atomicAdd(&cur[d4.w >> BSH], 1);
        ebuf[p0] = make_int2(s4.x, d4.x);
        ebuf[p1] = make_int2(s4.y, d4.y);
        ebuf[p2] = make_int2(s4.z, d4.z);
        ebuf[p3] = make_int2(s4.w, d4.w);
    }
    if (tid < (end - beg) - nfull) {
        int i = beg + nfull + tid;
        int d = dst[i];
        int p = atomicAdd(&cur[d >> BSH], 1);
        ebuf[p] = make_int2(src[i], d);
    }
}

// P2a: per bucket: LDS hist over 512 local nodes -> scan -> row_ptr, dinv
__global__ __launch_bounds__(TPB)
void k_p2rowptr(const int2* __restrict__ ebuf, const int* __restrict__ OFS,
                int* __restrict__ row_ptr, float* __restrict__ dinv,
                int N, int E, int NBC) {
    __shared__ int cnt[BNODES];
    __shared__ int s1[TPB];
    int tid = threadIdx.x, c = blockIdx.x;
    int beg = OFS[c * EBLKS], end = OFS[(c + 1) * EBLKS];
    for (int i = tid; i < BNODES; i += TPB) cnt[i] = 0;
    __syncthreads();
    for (int i = beg + tid; i < end; i += TPB)
        atomicAdd(&cnt[ebuf[i].y & (BNODES - 1)], 1);
    __syncthreads();
    int a0 = cnt[2 * tid], a1 = cnt[2 * tid + 1];
    int pairsum = a0 + a1;
    s1[tid] = pairsum;
    __syncthreads();
    for (int off = 1; off < TPB; off <<= 1) {
        int x = (tid >= off) ? s1[tid - off] : 0;
        __syncthreads();
        s1[tid] += x;
        __syncthreads();
    }
    int ex = s1[tid] - pairsum;
    int node0 = (c << BSH) + 2 * tid;
    if (node0 < N) {
        row_ptr[node0] = beg + ex;
        dinv[node0]    = rsqrtf((float)(a0 + 1));
    }
    if (node0 + 1 < N) {
        row_ptr[node0 + 1] = beg + ex + a0;
        dinv[node0 + 1]    = rsqrtf((float)(a1 + 1));
    }
    if (c == NBC - 1 && tid == 0) row_ptr[N] = E;
}

// P2b: per bucket: LDS rank -> colw[row_ptr[d]+rank] = {src, dinv[s]*dinv[d]}
__global__ __launch_bounds__(TPB)
void k_p2fill(const int2* __restrict__ ebuf, const int* __restrict__ OFS,
              const int* __restrict__ row_ptr, const float* __restrict__ dinv,
              int2* __restrict__ colw, int NBC) {
    __shared__ int cnt[BNODES];
    int tid = threadIdx.x, c = blockIdx.x;
    int beg = OFS[c * EBLKS], end = OFS[(c + 1) * EBLKS];
    for (int i = tid; i < BNODES; i += TPB) cnt[i] = 0;
    __syncthreads();
    for (int i0 = beg + tid; i0 < end; i0 += TPB * 4) {
        int2  e[4];
        int   pos[4];
        float w[4];
        int   have = 0;
#pragma unroll
        for (int k = 0; k < 4; ++k) {
            int i = i0 + k * TPB;
            if (i < end) { e[k] = ebuf[i]; have = k + 1; }
        }
#pragma unroll
        for (int k = 0; k < 4; ++k) {
            if (k < have) {
                int r  = atomicAdd(&cnt[e[k].y & (BNODES - 1)], 1);
                pos[k] = row_ptr[e[k].y] + r;
                w[k]   = dinv[e[k].x] * dinv[e[k].y];
            }
        }
#pragma unroll
        for (int k = 0; k < 4; ++k)
            if (k < have) colw[pos[k]] = make_int2(e[k].x, __float_as_int(w[k]));
    }
}

// Dense GEMM: [n,64] @ [64,F].
// HOUT: write t as fp16 (gather input). Else fp32 (+bias if FINAL).
template <int F, bool FINAL, bool HOUT>
__launch_bounds__(256)
__global__ void k_mm(const float* __restrict__ in, const float* __restrict__ W,
                     const float* __restrict__ bias,
                     void* __restrict__ t_out, int n) {
    __shared__ float in_s[64 * 68];
    __shared__ float w_s[64 * F];

    const int tid  = threadIdx.x;
    const int row0 = blockIdx.x * 64;

    for (int i4 = tid; i4 < (64 * F) / 4; i4 += 256)
        ((float4*)w_s)[i4] = ((const float4*)W)[i4];

    for (int idx = tid; idx < 64 * 16; idx += 256) {
        int r  = idx >> 4;
        int c4 = idx & 15;
        float4 v;
        if (row0 + r < n)
            v = *(const float4*)&in[(size_t)(row0 + r) * 64 + c4 * 4];
        else
            v = make_float4(0.f, 0.f, 0.f, 0.f);
        *(float4*)&in_s[r * 68 + c4 * 4] = v;
    }
    __syncthreads();

    constexpr int CPT = F / 16;
    const int tx = tid & 15;
    const int ty = tid >> 4;

    float acc[4][CPT];
#pragma unroll
    for (int r = 0; r < 4; ++r)
#pragma unroll
        for (int c = 0; c < CPT; ++c) acc[r][c] = 0.f;

#pragma unroll 4
    for (int k = 0; k < 64; ++k) {
        float b[CPT];
#pragma unroll
        for (int c = 0; c < CPT; ++c) b[c] = w_s[k * F + tx * CPT + c];
#pragma unroll
        for (int r = 0; r < 4; ++r) {
            float a = in_s[(ty * 4 + r) * 68 + k];
#pragma unroll
            for (int c = 0; c < CPT; ++c) acc[r][c] = fmaf(a, b[c], acc[r][c]);
        }
    }

#pragma unroll
    for (int r = 0; r < 4; ++r) {
        int row = row0 + ty * 4 + r;
        if (row >= n) continue;
        if constexpr (HOUT) {
            // CPT==4: pack 4 consecutive cols into 8 bytes
            __half2 p0 = __floats2half2_rn(acc[r][0], acc[r][1]);
            __half2 p1 = __floats2half2_rn(acc[r][2], acc[r][3]);
            uint2 u = make_uint2(*(unsigned*)&p0, *(unsigned*)&p1);
            *(uint2*)((__half*)t_out + (size_t)row * 64 + tx * 4) = u;
        } else {
#pragma unroll
            for (int c = 0; c < CPT; ++c) {
                int col = tx * CPT + c;
                float v = acc[r][c];
                if constexpr (FINAL) v += bias[col];
                ((float*)t_out)[(size_t)row * F + col] = v;
            }
        }
    }
}

// Gather aggregation: one wave per dst node. 4 lane-groups of 16; group g
// handles edge base+g; lane q=lane&15 covers features 4q..4q+3 via half4.
// No inner-loop shuffles; cross-group reduce (shfl_xor) once at the end.
// agg[d] = relu(bias + dinv[d]^2 * t[d] + sum_e w_e * t[src_e])
__global__ __launch_bounds__(256)
void k_gather(const int* __restrict__ row_ptr, const int2* __restrict__ colw,
              const float* __restrict__ dinv, const float* __restrict__ bias,
              const __half* __restrict__ t, float* __restrict__ agg, int N) {
    int gid  = blockIdx.x * blockDim.x + threadIdx.x;
    int d    = gid >> 6;
    int lane = threadIdx.x & 63;
    if (d >= N) return;
    int g = lane >> 4;        // edge group 0..3
    int q = lane & 15;        // feature quad

    int beg = row_ptr[d], end = row_ptr[d + 1];
    float4 acc = make_float4(0.f, 0.f, 0.f, 0.f);

    for (int base = beg; base < end; base += 8) {
        int e0 = base + g, e1 = base + 4 + g;
        // OOB edges get weight 0 and read row 0 (harmless)
        int2 cw0 = (e0 < end) ? colw[e0] : make_int2(0, 0);
        int2 cw1 = (e1 < end) ? colw[e1] : make_int2(0, 0);
        uint2 a0 = *(const uint2*)(t + (size_t)cw0.x * 64 + q * 4);
        uint2 a1 = *(const uint2*)(t + (size_t)cw1.x * 64 + q * 4);
        float w0 = __int_as_float(cw0.y);
        float w1 = __int_as_float(cw1.y);
        float2 f00 = __half22float2(*(__half2*)&a0.x);
        float2 f01 = __half22float2(*(__half2*)&a0.y);
        float2 f10 = __half22float2(*(__half2*)&a1.x);
        float2 f11 = __half22float2(*(__half2*)&a1.y);
        acc.x = fmaf(w0, f00.x, acc.x);
        acc.y = fmaf(w0, f00.y, acc.y);
        acc.z = fmaf(w0, f01.x, acc.z);
        acc.w = fmaf(w0, f01.y, acc.w);
        acc.x = fmaf(w1, f10.x, acc.x);
        acc.y = fmaf(w1, f10.y, acc.y);
        acc.z = fmaf(w1, f11.x, acc.z);
        acc.w = fmaf(w1, f11.y, acc.w);
    }

    // reduce across the 4 groups (lanes q, q+16, q+32, q+48)
    acc.x += __shfl_xor(acc.x, 32); acc.y += __shfl_xor(acc.y, 32);
    acc.z += __shfl_xor(acc.z, 32); acc.w += __shfl_xor(acc.w, 32);
    acc.x += __shfl_xor(acc.x, 16); acc.y += __shfl_xor(acc.y, 16);
    acc.z += __shfl_xor(acc.z, 16); acc.w += __shfl_xor(acc.w, 16);

    if (g == 0) {
        float dd = dinv[d];
        float w2 = dd * dd;
        uint2 as = *(const uint2*)(t + (size_t)d * 64 + q * 4);
        float2 s0 = __half22float2(*(__half2*)&as.x);
        float2 s1 = __half22float2(*(__half2*)&as.y);
        float4 b4 = *(const float4*)&bias[q * 4];
        float4 o;
        o.x = fmaxf(fmaf(w2, s0.x, acc.x) + b4.x, 0.f);
        o.y = fmaxf(fmaf(w2, s0.y, acc.y) + b4.y, 0.f);
        o.z = fmaxf(fmaf(w2, s1.x, acc.z) + b4.z, 0.f);
        o.w = fmaxf(fmaf(w2, s1.y, acc.w) + b4.w, 0.f);
        *(float4*)&agg[(size_t)d * 64 + q * 4] = o;
    }
}

extern "C" void kernel_launch(void* const* d_in, const int* in_sizes, int n_in,
                              void* d_out, int out_size, void* d_ws, size_t ws_size,
                              hipStream_t stream) {
    const float* x  = (const float*)d_in[0];
    const int*   ei = (const int*)d_in[1];
    const float* W1 = (const float*)d_in[2];
    const float* b1 = (const float*)d_in[3];
    const float* W2 = (const float*)d_in[4];
    const float* b2 = (const float*)d_in[5];
    const float* Wl = (const float*)d_in[6];
    const float* bl = (const float*)d_in[7];
    float*       out = (float*)d_out;

    const int N = in_sizes[0] / 64;
    const int E = in_sizes[1] / 2;
    const int* srcp = ei;
    const int* dstp = ei + E;

    const int NBC   = (N + BNODES - 1) / BNODES;             // buckets
    const int CH    = (((E + EBLKS - 1) / EBLKS) + 3) & ~3;  // chunk, mult of 4
    const int total = NBC * EBLKS;                           // offset matrix
    const int NBLK  = (total + 1023) / 1024;                 // scan blocks

    char*  ws  = (char*)d_ws;
    size_t off = 0;
    auto alloc = [&](size_t bytes) -> void* {
        void* p = (void*)(ws + off);
        off += (bytes + 255) & ~(size_t)255;
        return p;
    };
    int*    OFS     = (int*)alloc(((size_t)total + 1) * 4);
    int*    bsum    = (int*)alloc((size_t)NBLK * 4);
    int2*   ebuf    = (int2*)alloc((size_t)E * 8);
    int*    row_ptr = (int*)alloc((size_t)(N + 1) * 4);
    float*  dinv    = (float*)alloc((size_t)N * 4);
    int2*   colw    = (int2*)alloc((size_t)E * 8);
    __half* t       = (__half*)alloc((size_t)N * 64 * 2);
    float*  agg1    = (float*)alloc((size_t)N * 64 * 4);
    float*  agg2    = agg1;   // safe: agg1 dead once mm2 wrote t

    const int nb_mm = (N + 63) / 64;
    const int nb_g  = (int)(((size_t)N * 64 + 255) / 256);

    // --- CSR build (no global atomics) ---
    k_p1hist   <<<EBLKS, TPB, 0, stream>>>(dstp, OFS, E, CH, NBC);
    k_scanA    <<<NBLK,  TPB, 0, stream>>>(OFS, bsum, total);
    k_scanB    <<<1,     TPB, 0, stream>>>(bsum, OFS, NBLK, total, E);
    k_scanC    <<<NBLK,  TPB, 0, stream>>>(OFS, bsum, total);
    k_p1scatter<<<EBLKS, TPB, 0, stream>>>(srcp, dstp, OFS, ebuf, E, CH, NBC);
    k_p2rowptr <<<NBC,   TPB, 0, stream>>>(ebuf, OFS, row_ptr, dinv, N, E, NBC);
    k_p2fill   <<<NBC,   TPB, 0, stream>>>(ebuf, OFS, row_ptr, dinv, colw, NBC);

    // --- layer 1 ---
    k_mm<64, false, true><<<nb_mm, 256, 0, stream>>>(x, W1, nullptr, t, N);
    k_gather<<<nb_g, 256, 0, stream>>>(row_ptr, colw, dinv, b1, t, agg1, N);

    // --- layer 2 ---
    k_mm<64, false, true><<<nb_mm, 256, 0, stream>>>(agg1, W2, nullptr, t, N);
    k_gather<<<nb_g, 256, 0, stream>>>(row_ptr, colw, dinv, b2, t, agg2, N);

    // --- head ---
    k_mm<32, true, false><<<nb_mm, 256, 0, stream>>>(agg2, Wl, bl, out, N);
}

// Round 8
// 246.954 us; speedup vs baseline: 1.0441x; 1.0441x over previous
//
#include <hip/hip_runtime.h>
#include <hip/hip_fp16.h>
#include <math.h>

// ---------------------------------------------------------------------------
// GCN. CSR build = bucketed counting sort, LDS atomics only (no global
// atomics: device-scope atomic-returns run memory-side at ~23 Gops/s on
// multi-XCD CDNA4 — measured R3/R4 — so they are banned here).
// Aggregation: atomic-free gather; t stored fp16; per node: one coalesced
// colw block load -> register shfl broadcast -> 8-edge gather batches with
// one 16B/lane load instruction per batch (no load-load dependency chain).
// ---------------------------------------------------------------------------

#define TPB    256
#define EBLKS  256          // pass-1 edge blocks (256 -> all CUs busy)
#define BSH    9            // 512 nodes per bucket
#define BNODES (1 << BSH)

// P1a: OFS[c*EBLKS + b] = #edges of bucket c in block b's chunk
__global__ __launch_bounds__(TPB)
void k_p1hist(const int* __restrict__ dst, int* __restrict__ OFS,
              int E, int CH, int NBC) {
    __shared__ int h[512];
    int tid = threadIdx.x, b = blockIdx.x;
    for (int i = tid; i < NBC; i += TPB) h[i] = 0;
    __syncthreads();
    int beg = b * CH, end = min(E, beg + CH);
    if (beg < end) {
        int nfull = (end - beg) & ~3;
        for (int i = beg + tid * 4; i < beg + nfull; i += TPB * 4) {
            int4 d = *(const int4*)&dst[i];
            atomicAdd(&h[d.x >> BSH], 1);
            atomicAdd(&h[d.y >> BSH], 1);
            atomicAdd(&h[d.z >> BSH], 1);
            atomicAdd(&h[d.w >> BSH], 1);
        }
        if (tid < (end - beg) - nfull)
            atomicAdd(&h[dst[beg + nfull + tid] >> BSH], 1);
    }
    __syncthreads();
    for (int c = tid; c < NBC; c += TPB) OFS[c * EBLKS + b] = h[c];
}

// Hierarchical exclusive scan of OFS[0..total)
__global__ __launch_bounds__(TPB)
void k_scanA(const int* __restrict__ OFS, int* __restrict__ bsum, int total) {
    __shared__ int s[TPB];
    int tid = threadIdx.x;
    int i0  = blockIdx.x * 1024 + tid * 4;
    int t = 0;
#pragma unroll
    for (int k = 0; k < 4; ++k) {
        int i = i0 + k;
        t += (i < total) ? OFS[i] : 0;
    }
    s[tid] = t;
    __syncthreads();
    for (int off = TPB / 2; off > 0; off >>= 1) {
        if (tid < off) s[tid] += s[tid + off];
        __syncthreads();
    }
    if (tid == 0) bsum[blockIdx.x] = s[0];
}

__global__ __launch_bounds__(TPB)
void k_scanB(int* bsum, int* OFS, int NBLK, int total, int E) {
    __shared__ int s[TPB];
    int tid = threadIdx.x;
    int v = (tid < NBLK) ? bsum[tid] : 0;
    s[tid] = v;
    __syncthreads();
    for (int off = 1; off < TPB; off <<= 1) {
        int x = (tid >= off) ? s[tid - off] : 0;
        __syncthreads();
        s[tid] += x;
        __syncthreads();
    }
    if (tid < NBLK) bsum[tid] = s[tid] - v;   // exclusive
    if (tid == 0) OFS[total] = E;             // sentinel
}

__global__ __launch_bounds__(TPB)
void k_scanC(int* __restrict__ OFS, const int* __restrict__ bsum, int total) {
    __shared__ int s[TPB];
    int tid = threadIdx.x;
    int i0  = blockIdx.x * 1024 + tid * 4;
    int v[4];
#pragma unroll
    for (int k = 0; k < 4; ++k) {
        int i = i0 + k;
        v[k] = (i < total) ? OFS[i] : 0;
    }
    int tsum = v[0] + v[1] + v[2] + v[3];
    s[tid] = tsum;
    __syncthreads();
    for (int off = 1; off < TPB; off <<= 1) {
        int x = (tid >= off) ? s[tid - off] : 0;
        __syncthreads();
        s[tid] += x;
        __syncthreads();
    }
    int base = bsum[blockIdx.x] + (s[tid] - tsum);
#pragma unroll
    for (int k = 0; k < 4; ++k) {
        int i = i0 + k;
        if (i < total) {
            OFS[i] = base;
            base += v[k];
        }
    }
}

// P1c: scatter (src,dst) into bucket-contiguous ebuf via LDS cursors
__global__ __launch_bounds__(TPB)
void k_p1scatter(const int* __restrict__ src, const int* __restrict__ dst,
                 const int* __restrict__ OFS, int2* __restrict__ ebuf,
                 int E, int CH, int NBC) {
    __shared__ int cur[512];
    int tid = threadIdx.x, b = blockIdx.x;
    for (int c = tid; c < NBC; c += TPB) cur[c] = OFS[c * EBLKS + b];
    __syncthreads();
    int beg = b * CH, end = min(E, beg + CH);
    if (beg >= end) return;
    int nfull = (end - beg) & ~3;
    for (int i = beg + tid * 4; i < beg + nfull; i += TPB * 4) {
        int4 s4 = *(const int4*)&src[i];
        int4 d4 = *(const int4*)&dst[i];
        int p0 = atomicAdd(&cur[d4.x >> BSH], 1);
        int p1 = atomicAdd(&cur[d4.y >> BSH], 1);
        int p2 = atomicAdd(&cur[d4.z >> BSH], 1);
        int p3 = atomicAdd(&cur[d4.w >> BSH], 1);
        ebuf[p0] = make_int2(s4.x, d4.x);
        ebuf[p1] = make_int2(s4.y, d4.y);
        ebuf[p2] = make_int2(s4.z, d4.z);
        ebuf[p3] = make_int2(s4.w, d4.w);
    }
    if (tid < (end - beg) - nfull) {
        int i = beg + nfull + tid;
        int d = dst[i];
        int p = atomicAdd(&cur[d >> BSH], 1);
        ebuf[p] = make_int2(src[i], d);
    }
}

// P2a: per bucket: LDS hist over 512 local nodes -> scan -> row_ptr, dinv
__global__ __launch_bounds__(TPB)
void k_p2rowptr(const int2* __restrict__ ebuf, const int* __restrict__ OFS,
                int* __restrict__ row_ptr, float* __restrict__ dinv,
                int N, int E, int NBC) {
    __shared__ int cnt[BNODES];
    __shared__ int s1[TPB];
    int tid = threadIdx.x, c = blockIdx.x;
    int beg = OFS[c * EBLKS], end = OFS[(c + 1) * EBLKS];
    for (int i = tid; i < BNODES; i += TPB) cnt[i] = 0;
    __syncthreads();
    for (int i = beg + tid; i < end; i += TPB)
        atomicAdd(&cnt[ebuf[i].y & (BNODES - 1)], 1);
    __syncthreads();
    int a0 = cnt[2 * tid], a1 = cnt[2 * tid + 1];
    int pairsum = a0 + a1;
    s1[tid] = pairsum;
    __syncthreads();
    for (int off = 1; off < TPB; off <<= 1) {
        int x = (tid >= off) ? s1[tid - off] : 0;
        __syncthreads();
        s1[tid] += x;
        __syncthreads();
    }
    int ex = s1[tid] - pairsum;
    int node0 = (c << BSH) + 2 * tid;
    if (node0 < N) {
        row_ptr[node0] = beg + ex;
        dinv[node0]    = rsqrtf((float)(a0 + 1));
    }
    if (node0 + 1 < N) {
        row_ptr[node0 + 1] = beg + ex + a0;
        dinv[node0 + 1]    = rsqrtf((float)(a1 + 1));
    }
    if (c == NBC - 1 && tid == 0) row_ptr[N] = E;
}

// P2b: per bucket: LDS rank -> colw[row_ptr[d]+rank] = {src, dinv[s]*dinv[d]}
__global__ __launch_bounds__(TPB)
void k_p2fill(const int2* __restrict__ ebuf, const int* __restrict__ OFS,
              const int* __restrict__ row_ptr, const float* __restrict__ dinv,
              int2* __restrict__ colw, int NBC) {
    __shared__ int cnt[BNODES];
    int tid = threadIdx.x, c = blockIdx.x;
    int beg = OFS[c * EBLKS], end = OFS[(c + 1) * EBLKS];
    for (int i = tid; i < BNODES; i += TPB) cnt[i] = 0;
    __syncthreads();
    for (int i0 = beg + tid; i0 < end; i0 += TPB * 4) {
        int2  e[4];
        int   pos[4];
        float w[4];
        int   have = 0;
#pragma unroll
        for (int k = 0; k < 4; ++k) {
            int i = i0 + k * TPB;
            if (i < end) { e[k] = ebuf[i]; have = k + 1; }
        }
#pragma unroll
        for (int k = 0; k < 4; ++k) {
            if (k < have) {
                int r  = atomicAdd(&cnt[e[k].y & (BNODES - 1)], 1);
                pos[k] = row_ptr[e[k].y] + r;
                w[k]   = dinv[e[k].x] * dinv[e[k].y];
            }
        }
#pragma unroll
        for (int k = 0; k < 4; ++k)
            if (k < have) colw[pos[k]] = make_int2(e[k].x, __float_as_int(w[k]));
    }
}

// Dense GEMM: [n,64] @ [64,F].
// HOUT: write t as fp16 (gather input). Else fp32 (+bias if FINAL).
template <int F, bool FINAL, bool HOUT>
__launch_bounds__(256)
__global__ void k_mm(const float* __restrict__ in, const float* __restrict__ W,
                     const float* __restrict__ bias,
                     void* __restrict__ t_out, int n) {
    __shared__ float in_s[64 * 68];
    __shared__ float w_s[64 * F];

    const int tid  = threadIdx.x;
    const int row0 = blockIdx.x * 64;

    for (int i4 = tid; i4 < (64 * F) / 4; i4 += 256)
        ((float4*)w_s)[i4] = ((const float4*)W)[i4];

    for (int idx = tid; idx < 64 * 16; idx += 256) {
        int r  = idx >> 4;
        int c4 = idx & 15;
        float4 v;
        if (row0 + r < n)
            v = *(const float4*)&in[(size_t)(row0 + r) * 64 + c4 * 4];
        else
            v = make_float4(0.f, 0.f, 0.f, 0.f);
        *(float4*)&in_s[r * 68 + c4 * 4] = v;
    }
    __syncthreads();

    constexpr int CPT = F / 16;
    const int tx = tid & 15;
    const int ty = tid >> 4;

    float acc[4][CPT];
#pragma unroll
    for (int r = 0; r < 4; ++r)
#pragma unroll
        for (int c = 0; c < CPT; ++c) acc[r][c] = 0.f;

#pragma unroll 4
    for (int k = 0; k < 64; ++k) {
        float b[CPT];
#pragma unroll
        for (int c = 0; c < CPT; ++c) b[c] = w_s[k * F + tx * CPT + c];
#pragma unroll
        for (int r = 0; r < 4; ++r) {
            float a = in_s[(ty * 4 + r) * 68 + k];
#pragma unroll
            for (int c = 0; c < CPT; ++c) acc[r][c] = fmaf(a, b[c], acc[r][c]);
        }
    }

#pragma unroll
    for (int r = 0; r < 4; ++r) {
        int row = row0 + ty * 4 + r;
        if (row >= n) continue;
        if constexpr (HOUT) {
            // CPT==4: pack 4 consecutive cols into 8 bytes
            __half2 p0 = __floats2half2_rn(acc[r][0], acc[r][1]);
            __half2 p1 = __floats2half2_rn(acc[r][2], acc[r][3]);
            uint2 u = make_uint2(*(unsigned*)&p0, *(unsigned*)&p1);
            *(uint2*)((__half*)t_out + (size_t)row * 64 + tx * 4) = u;
        } else {
#pragma unroll
            for (int c = 0; c < CPT; ++c) {
                int col = tx * CPT + c;
                float v = acc[r][c];
                if constexpr (FINAL) v += bias[col];
                ((float*)t_out)[(size_t)row * F + col] = v;
            }
        }
    }
}

// Gather aggregation: one wave per dst node.
// Step 1: lane l preloads colw[beg+l] (covers deg<=64 in one coalesced load).
// Step 2: batches of 8 edges; 8 groups x 8 lanes; group g takes edge j+g,
//         lane p=lane&7 loads uint4 (16B = 8 fp16 feats) -> one load instr
//         per batch, addresses from registers (no load->load dependency).
// Step 3: xor-reduce across groups; lanes 0..7 do self-loop+bias+relu+store.
__global__ __launch_bounds__(256)
void k_gather(const int* __restrict__ row_ptr, const int2* __restrict__ colw,
              const float* __restrict__ dinv, const float* __restrict__ bias,
              const __half* __restrict__ t, float* __restrict__ agg, int N) {
    int gid  = blockIdx.x * blockDim.x + threadIdx.x;
    int d    = gid >> 6;
    int lane = threadIdx.x & 63;
    if (d >= N) return;
    int g = lane >> 3;        // edge group 0..7
    int p = lane & 7;         // feature octet (8 halves = 16B)

    int beg = row_ptr[d], end = row_ptr[d + 1];
    float acc[8];
#pragma unroll
    for (int k = 0; k < 8; ++k) acc[k] = 0.f;

    for (int base = beg; base < end; base += 64) {
        int nb = min(64, end - base);
        // inactive lanes: weight 0, src 0 (reads hot row 0, contributes 0)
        int2 cw = (lane < nb) ? colw[base + lane] : make_int2(0, 0);
        for (int j = 0; j < nb; j += 8) {
            int   sj = __shfl(cw.x, j + g);
            float wj = __int_as_float(__shfl(cw.y, j + g));
            uint4 a  = *(const uint4*)(t + (size_t)sj * 64 + p * 8);
            float2 f0 = __half22float2(*(__half2*)&a.x);
            float2 f1 = __half22float2(*(__half2*)&a.y);
            float2 f2 = __half22float2(*(__half2*)&a.z);
            float2 f3 = __half22float2(*(__half2*)&a.w);
            acc[0] = fmaf(wj, f0.x, acc[0]);
            acc[1] = fmaf(wj, f0.y, acc[1]);
            acc[2] = fmaf(wj, f1.x, acc[2]);
            acc[3] = fmaf(wj, f1.y, acc[3]);
            acc[4] = fmaf(wj, f2.x, acc[4]);
            acc[5] = fmaf(wj, f2.y, acc[5]);
            acc[6] = fmaf(wj, f3.x, acc[6]);
            acc[7] = fmaf(wj, f3.y, acc[7]);
        }
    }

    // reduce across the 8 groups (lane bits 3..5)
#pragma unroll
    for (int k = 0; k < 8; ++k) {
        acc[k] += __shfl_xor(acc[k], 8);
        acc[k] += __shfl_xor(acc[k], 16);
        acc[k] += __shfl_xor(acc[k], 32);
    }

    if (g == 0) {
        float dd = dinv[d];
        float w2 = dd * dd;
        uint4 a = *(const uint4*)(t + (size_t)d * 64 + p * 8);
        float2 s0 = __half22float2(*(__half2*)&a.x);
        float2 s1 = __half22float2(*(__half2*)&a.y);
        float2 s2 = __half22float2(*(__half2*)&a.z);
        float2 s3 = __half22float2(*(__half2*)&a.w);
        float4 b0 = *(const float4*)&bias[p * 8];
        float4 b1 = *(const float4*)&bias[p * 8 + 4];
        float4 o0, o1;
        o0.x = fmaxf(fmaf(w2, s0.x, acc[0]) + b0.x, 0.f);
        o0.y = fmaxf(fmaf(w2, s0.y, acc[1]) + b0.y, 0.f);
        o0.z = fmaxf(fmaf(w2, s1.x, acc[2]) + b0.z, 0.f);
        o0.w = fmaxf(fmaf(w2, s1.y, acc[3]) + b0.w, 0.f);
        o1.x = fmaxf(fmaf(w2, s2.x, acc[4]) + b1.x, 0.f);
        o1.y = fmaxf(fmaf(w2, s2.y, acc[5]) + b1.y, 0.f);
        o1.z = fmaxf(fmaf(w2, s3.x, acc[6]) + b1.z, 0.f);
        o1.w = fmaxf(fmaf(w2, s3.y, acc[7]) + b1.w, 0.f);
        *(float4*)&agg[(size_t)d * 64 + p * 8]     = o0;
        *(float4*)&agg[(size_t)d * 64 + p * 8 + 4] = o1;
    }
}

extern "C" void kernel_launch(void* const* d_in, const int* in_sizes, int n_in,
                              void* d_out, int out_size, void* d_ws, size_t ws_size,
                              hipStream_t stream) {
    const float* x  = (const float*)d_in[0];
    const int*   ei = (const int*)d_in[1];
    const float* W1 = (const float*)d_in[2];
    const float* b1 = (const float*)d_in[3];
    const float* W2 = (const float*)d_in[4];
    const float* b2 = (const float*)d_in[5];
    const float* Wl = (const float*)d_in[6];
    const float* bl = (const float*)d_in[7];
    float*       out = (float*)d_out;

    const int N = in_sizes[0] / 64;
    const int E = in_sizes[1] / 2;
    const int* srcp = ei;
    const int* dstp = ei + E;

    const int NBC   = (N + BNODES - 1) / BNODES;             // buckets
    const int CH    = (((E + EBLKS - 1) / EBLKS) + 3) & ~3;  // chunk, mult of 4
    const int total = NBC * EBLKS;                           // offset matrix
    const int NBLK  = (total + 1023) / 1024;                 // scan blocks

    char*  ws  = (char*)d_ws;
    size_t off = 0;
    auto alloc = [&](size_t bytes) -> void* {
        void* p = (void*)(ws + off);
        off += (bytes + 255) & ~(size_t)255;
        return p;
    };
    int*    OFS     = (int*)alloc(((size_t)total + 1) * 4);
    int*    bsum    = (int*)alloc((size_t)NBLK * 4);
    int2*   ebuf    = (int2*)alloc((size_t)E * 8);
    int*    row_ptr = (int*)alloc((size_t)(N + 1) * 4);
    float*  dinv    = (float*)alloc((size_t)N * 4);
    int2*   colw    = (int2*)alloc((size_t)E * 8);
    __half* t       = (__half*)alloc((size_t)N * 64 * 2);
    float*  agg1    = (float*)alloc((size_t)N * 64 * 4);
    float*  agg2    = agg1;   // safe: agg1 dead once mm2 wrote t

    const int nb_mm = (N + 63) / 64;
    const int nb_g  = (int)(((size_t)N * 64 + 255) / 256);

    // --- CSR build (no global atomics) ---
    k_p1hist   <<<EBLKS, TPB, 0, stream>>>(dstp, OFS, E, CH, NBC);
    k_scanA    <<<NBLK,  TPB, 0, stream>>>(OFS, bsum, total);
    k_scanB    <<<1,     TPB, 0, stream>>>(bsum, OFS, NBLK, total, E);
    k_scanC    <<<NBLK,  TPB, 0, stream>>>(OFS, bsum, total);
    k_p1scatter<<<EBLKS, TPB, 0, stream>>>(srcp, dstp, OFS, ebuf, E, CH, NBC);
    k_p2rowptr <<<NBC,   TPB, 0, stream>>>(ebuf, OFS, row_ptr, dinv, N, E, NBC);
    k_p2fill   <<<NBC,   TPB, 0, stream>>>(ebuf, OFS, row_ptr, dinv, colw, NBC);

    // --- layer 1 ---
    k_mm<64, false, true><<<nb_mm, 256, 0, stream>>>(x, W1, nullptr, t, N);
    k_gather<<<nb_g, 256, 0, stream>>>(row_ptr, colw, dinv, b1, t, agg1, N);

    // --- layer 2 ---
    k_mm<64, false, true><<<nb_mm, 256, 0, stream>>>(agg1, W2, nullptr, t, N);
    k_gather<<<nb_g, 256, 0, stream>>>(row_ptr, colw, dinv, b2, t, agg2, N);

    // --- head ---
    k_mm<32, true, false><<<nb_mm, 256, 0, stream>>>(agg2, Wl, bl, out, N);
}

// Round 9
// 217.359 us; speedup vs baseline: 1.1862x; 1.1362x over previous
//
#include <hip/hip_runtime.h>
#include <hip/hip_fp16.h>
#include <math.h>

// ---------------------------------------------------------------------------
// GCN. CSR build = bucketed counting sort, LDS atomics only (no global
// atomics: device-scope atomic-returns run memory-side at ~23 Gops/s on
// multi-XCD CDNA4 — measured R3/R4). ebuf packed (src<<9|local) in 4 B.
// Aggregation: 8 nodes/wave, 8 lanes/node, broadcast colw loads, no
// shuffles, fp16 t and fp16 agg (fp32 accumulate in registers).
// ---------------------------------------------------------------------------

#define TPB    256
#define EBLKS  256          // pass-1 edge blocks (256 -> all CUs busy)
#define BSH    9            // 512 nodes per bucket
#define BNODES (1 << BSH)

// P1a: OFS[c*EBLKS + b] = #edges of bucket c in block b's chunk
__global__ __launch_bounds__(TPB)
void k_p1hist(const int* __restrict__ dst, int* __restrict__ OFS,
              int E, int CH, int NBC) {
    __shared__ int h[512];
    int tid = threadIdx.x, b = blockIdx.x;
    for (int i = tid; i < NBC; i += TPB) h[i] = 0;
    __syncthreads();
    int beg = b * CH, end = min(E, beg + CH);
    if (beg < end) {
        int nfull = (end - beg) & ~3;
        for (int i = beg + tid * 4; i < beg + nfull; i += TPB * 4) {
            int4 d = *(const int4*)&dst[i];
            atomicAdd(&h[d.x >> BSH], 1);
            atomicAdd(&h[d.y >> BSH], 1);
            atomicAdd(&h[d.z >> BSH], 1);
            atomicAdd(&h[d.w >> BSH], 1);
        }
        if (tid < (end - beg) - nfull)
            atomicAdd(&h[dst[beg + nfull + tid] >> BSH], 1);
    }
    __syncthreads();
    for (int c = tid; c < NBC; c += TPB) OFS[c * EBLKS + b] = h[c];
}

// Hierarchical exclusive scan of OFS[0..total)
__global__ __launch_bounds__(TPB)
void k_scanA(const int* __restrict__ OFS, int* __restrict__ bsum, int total) {
    __shared__ int s[TPB];
    int tid = threadIdx.x;
    int i0  = blockIdx.x * 1024 + tid * 4;
    int t = 0;
#pragma unroll
    for (int k = 0; k < 4; ++k) {
        int i = i0 + k;
        t += (i < total) ? OFS[i] : 0;
    }
    s[tid] = t;
    __syncthreads();
    for (int off = TPB / 2; off > 0; off >>= 1) {
        if (tid < off) s[tid] += s[tid + off];
        __syncthreads();
    }
    if (tid == 0) bsum[blockIdx.x] = s[0];
}

__global__ __launch_bounds__(TPB)
void k_scanB(int* bsum, int* OFS, int NBLK, int total, int E) {
    __shared__ int s[TPB];
    int tid = threadIdx.x;
    int v = (tid < NBLK) ? bsum[tid] : 0;
    s[tid] = v;
    __syncthreads();
    for (int off = 1; off < TPB; off <<= 1) {
        int x = (tid >= off) ? s[tid - off] : 0;
        __syncthreads();
        s[tid] += x;
        __syncthreads();
    }
    if (tid < NBLK) bsum[tid] = s[tid] - v;   // exclusive
    if (tid == 0) OFS[total] = E;             // sentinel
}

__global__ __launch_bounds__(TPB)
void k_scanC(int* __restrict__ OFS, const int* __restrict__ bsum, int total) {
    __shared__ int s[TPB];
    int tid = threadIdx.x;
    int i0  = blockIdx.x * 1024 + tid * 4;
    int v[4];
#pragma unroll
    for (int k = 0; k < 4; ++k) {
        int i = i0 + k;
        v[k] = (i < total) ? OFS[i] : 0;
    }
    int tsum = v[0] + v[1] + v[2] + v[3];
    s[tid] = tsum;
    __syncthreads();
    for (int off = 1; off < TPB; off <<= 1) {
        int x = (tid >= off) ? s[tid - off] : 0;
        __syncthreads();
        s[tid] += x;
        __syncthreads();
    }
    int base = bsum[blockIdx.x] + (s[tid] - tsum);
#pragma unroll
    for (int k = 0; k < 4; ++k) {
        int i = i0 + k;
        if (i < total) {
            OFS[i] = base;
            base += v[k];
        }
    }
}

// P1c: scatter packed (src<<9|local) into bucket-contiguous ebuf (LDS cursors)
__global__ __launch_bounds__(TPB)
void k_p1scatter(const int* __restrict__ src, const int* __restrict__ dst,
                 const int* __restrict__ OFS, int* __restrict__ ebuf,
                 int E, int CH, int NBC) {
    __shared__ int cur[512];
    int tid = threadIdx.x, b = blockIdx.x;
    for (int c = tid; c < NBC; c += TPB) cur[c] = OFS[c * EBLKS + b];
    __syncthreads();
    int beg = b * CH, end = min(E, beg + CH);
    if (beg >= end) return;
    int nfull = (end - beg) & ~3;
    for (int i = beg + tid * 4; i < beg + nfull; i += TPB * 4) {
        int4 s4 = *(const int4*)&src[i];
        int4 d4 = *(const int4*)&dst[i];
        int p0 = atomicAdd(&cur[d4.x >> BSH], 1);
        int p1 = atomicAdd(&cur[d4.y >> BSH], 1);
        int p2 = atomicAdd(&cur[d4.z >> BSH], 1);
        int p3 = atomicAdd(&cur[d4.w >> BSH], 1);
        ebuf[p0] = (s4.x << BSH) | (d4.x & (BNODES - 1));
        ebuf[p1] = (s4.y << BSH) | (d4.y & (BNODES - 1));
        ebuf[p2] = (s4.z << BSH) | (d4.z & (BNODES - 1));
        ebuf[p3] = (s4.w << BSH) | (d4.w & (BNODES - 1));
    }
    if (tid < (end - beg) - nfull) {
        int i = beg + nfull + tid;
        int d = dst[i];
        int p = atomicAdd(&cur[d >> BSH], 1);
        ebuf[p] = (src[i] << BSH) | (d & (BNODES - 1));
    }
}

// P2a: per bucket: LDS hist over 512 local nodes -> scan -> row_ptr, dinv
__global__ __launch_bounds__(TPB)
void k_p2rowptr(const int* __restrict__ ebuf, const int* __restrict__ OFS,
                int* __restrict__ row_ptr, float* __restrict__ dinv,
                int N, int E, int NBC) {
    __shared__ int cnt[BNODES];
    __shared__ int s1[TPB];
    int tid = threadIdx.x, c = blockIdx.x;
    int beg = OFS[c * EBLKS], end = OFS[(c + 1) * EBLKS];
    for (int i = tid; i < BNODES; i += TPB) cnt[i] = 0;
    __syncthreads();
    for (int i = beg + tid; i < end; i += TPB)
        atomicAdd(&cnt[ebuf[i] & (BNODES - 1)], 1);
    __syncthreads();
    int a0 = cnt[2 * tid], a1 = cnt[2 * tid + 1];
    int pairsum = a0 + a1;
    s1[tid] = pairsum;
    __syncthreads();
    for (int off = 1; off < TPB; off <<= 1) {
        int x = (tid >= off) ? s1[tid - off] : 0;
        __syncthreads();
        s1[tid] += x;
        __syncthreads();
    }
    int ex = s1[tid] - pairsum;
    int node0 = (c << BSH) + 2 * tid;
    if (node0 < N) {
        row_ptr[node0] = beg + ex;
        dinv[node0]    = rsqrtf((float)(a0 + 1));
    }
    if (node0 + 1 < N) {
        row_ptr[node0 + 1] = beg + ex + a0;
        dinv[node0 + 1]    = rsqrtf((float)(a1 + 1));
    }
    if (c == NBC - 1 && tid == 0) row_ptr[N] = E;
}

// P2b: per bucket: LDS rank -> colw[row_ptr[d]+rank] = {src, dinv[s]*dinv[d]}
__global__ __launch_bounds__(TPB)
void k_p2fill(const int* __restrict__ ebuf, const int* __restrict__ OFS,
              const int* __restrict__ row_ptr, const float* __restrict__ dinv,
              int2* __restrict__ colw, int NBC) {
    __shared__ int cnt[BNODES];
    int tid = threadIdx.x, c = blockIdx.x;
    int beg = OFS[c * EBLKS], end = OFS[(c + 1) * EBLKS];
    int cbase = c << BSH;
    for (int i = tid; i < BNODES; i += TPB) cnt[i] = 0;
    __syncthreads();
    for (int i0 = beg + tid; i0 < end; i0 += TPB * 4) {
        int   sv[4], dl[4], pos[4];
        float w[4];
        int   have = 0;
#pragma unroll
        for (int k = 0; k < 4; ++k) {
            int i = i0 + k * TPB;
            if (i < end) {
                int e = ebuf[i];
                sv[k] = e >> BSH;
                dl[k] = e & (BNODES - 1);
                have = k + 1;
            }
        }
#pragma unroll
        for (int k = 0; k < 4; ++k) {
            if (k < have) {
                int r  = atomicAdd(&cnt[dl[k]], 1);
                pos[k] = row_ptr[cbase + dl[k]] + r;
                w[k]   = dinv[sv[k]] * dinv[cbase + dl[k]];
            }
        }
#pragma unroll
        for (int k = 0; k < 4; ++k)
            if (k < have) colw[pos[k]] = make_int2(sv[k], __float_as_int(w[k]));
    }
}

// Dense GEMM: [n,64] @ [64,F].
// HIN: input rows fp16. HOUT: write fp16. FINAL: +bias, fp32 out.
template <int F, bool FINAL, bool HIN, bool HOUT>
__launch_bounds__(256)
__global__ void k_mm(const void* __restrict__ in, const float* __restrict__ W,
                     const float* __restrict__ bias,
                     void* __restrict__ t_out, int n) {
    __shared__ float in_s[64 * 68];
    __shared__ float w_s[64 * F];

    const int tid  = threadIdx.x;
    const int row0 = blockIdx.x * 64;

    for (int i4 = tid; i4 < (64 * F) / 4; i4 += 256)
        ((float4*)w_s)[i4] = ((const float4*)W)[i4];

    if constexpr (HIN) {
        for (int idx = tid; idx < 64 * 8; idx += 256) {
            int r  = idx >> 3;
            int c8 = idx & 7;
            uint4 u = make_uint4(0u, 0u, 0u, 0u);
            if (row0 + r < n)
                u = *(const uint4*)((const __half*)in + (size_t)(row0 + r) * 64 + c8 * 8);
            float2 f0 = __half22float2(*(__half2*)&u.x);
            float2 f1 = __half22float2(*(__half2*)&u.y);
            float2 f2 = __half22float2(*(__half2*)&u.z);
            float2 f3 = __half22float2(*(__half2*)&u.w);
            float* o = &in_s[r * 68 + c8 * 8];
            *(float4*)&o[0] = make_float4(f0.x, f0.y, f1.x, f1.y);
            *(float4*)&o[4] = make_float4(f2.x, f2.y, f3.x, f3.y);
        }
    } else {
        for (int idx = tid; idx < 64 * 16; idx += 256) {
            int r  = idx >> 4;
            int c4 = idx & 15;
            float4 v;
            if (row0 + r < n)
                v = *(const float4*)((const float*)in + (size_t)(row0 + r) * 64 + c4 * 4);
            else
                v = make_float4(0.f, 0.f, 0.f, 0.f);
            *(float4*)&in_s[r * 68 + c4 * 4] = v;
        }
    }
    __syncthreads();

    constexpr int CPT = F / 16;
    const int tx = tid & 15;
    const int ty = tid >> 4;

    float acc[4][CPT];
#pragma unroll
    for (int r = 0; r < 4; ++r)
#pragma unroll
        for (int c = 0; c < CPT; ++c) acc[r][c] = 0.f;

#pragma unroll 4
    for (int k = 0; k < 64; ++k) {
        float b[CPT];
#pragma unroll
        for (int c = 0; c < CPT; ++c) b[c] = w_s[k * F + tx * CPT + c];
#pragma unroll
        for (int r = 0; r < 4; ++r) {
            float a = in_s[(ty * 4 + r) * 68 + k];
#pragma unroll
            for (int c = 0; c < CPT; ++c) acc[r][c] = fmaf(a, b[c], acc[r][c]);
        }
    }

#pragma unroll
    for (int r = 0; r < 4; ++r) {
        int row = row0 + ty * 4 + r;
        if (row >= n) continue;
        if constexpr (HOUT) {
            __half2 p0 = __floats2half2_rn(acc[r][0], acc[r][1]);
            __half2 p1 = __floats2half2_rn(acc[r][2], acc[r][3]);
            uint2 u = make_uint2(*(unsigned*)&p0, *(unsigned*)&p1);
            *(uint2*)((__half*)t_out + (size_t)row * 64 + tx * 4) = u;
        } else {
#pragma unroll
            for (int c = 0; c < CPT; ++c) {
                int col = tx * CPT + c;
                float v = acc[r][c];
                if constexpr (FINAL) v += bias[col];
                ((float*)t_out)[(size_t)row * F + col] = v;
            }
        }
    }
}

// Gather aggregation: 8 nodes per wave, 8 lanes per node, no shuffles.
// Group g (lane>>3) owns node d; lane p=lane&7 covers features 8p..8p+7.
// colw[e] loaded by all 8 lanes of the group (HW broadcast); t row
// coalesced 8x16B. Edges unrolled x2 for MLP. fp32 accumulate, fp16 out.
// agg[d] = relu(bias + dinv[d]^2*t[d] + sum_e w_e*t[src_e])
__global__ __launch_bounds__(256)
void k_gather(const int* __restrict__ row_ptr, const int2* __restrict__ colw,
              const float* __restrict__ dinv, const float* __restrict__ bias,
              const __half* __restrict__ t, __half* __restrict__ agg, int N) {
    int tid  = threadIdx.x;
    int w    = tid >> 6;
    int lane = tid & 63;
    int g = lane >> 3;
    int p = lane & 7;
    int d = blockIdx.x * 32 + w * 8 + g;

    int beg = 0, end = 0;
    if (d < N) { beg = row_ptr[d]; end = row_ptr[d + 1]; }

    float acc[8];
#pragma unroll
    for (int k = 0; k < 8; ++k) acc[k] = 0.f;

    for (int e = beg; e < end; e += 2) {
        int2 cw0 = colw[e];
        int2 cw1 = (e + 1 < end) ? colw[e + 1] : make_int2(0, 0);
        uint4 a0 = *(const uint4*)(t + (size_t)cw0.x * 64 + p * 8);
        uint4 a1 = *(const uint4*)(t + (size_t)cw1.x * 64 + p * 8);
        float w0 = __int_as_float(cw0.y);
        float w1 = __int_as_float(cw1.y);
        float2 f;
        f = __half22float2(*(__half2*)&a0.x); acc[0] = fmaf(w0, f.x, acc[0]); acc[1] = fmaf(w0, f.y, acc[1]);
        f = __half22float2(*(__half2*)&a0.y); acc[2] = fmaf(w0, f.x, acc[2]); acc[3] = fmaf(w0, f.y, acc[3]);
        f = __half22float2(*(__half2*)&a0.z); acc[4] = fmaf(w0, f.x, acc[4]); acc[5] = fmaf(w0, f.y, acc[5]);
        f = __half22float2(*(__half2*)&a0.w); acc[6] = fmaf(w0, f.x, acc[6]); acc[7] = fmaf(w0, f.y, acc[7]);
        f = __half22float2(*(__half2*)&a1.x); acc[0] = fmaf(w1, f.x, acc[0]); acc[1] = fmaf(w1, f.y, acc[1]);
        f = __half22float2(*(__half2*)&a1.y); acc[2] = fmaf(w1, f.x, acc[2]); acc[3] = fmaf(w1, f.y, acc[3]);
        f = __half22float2(*(__half2*)&a1.z); acc[4] = fmaf(w1, f.x, acc[4]); acc[5] = fmaf(w1, f.y, acc[5]);
        f = __half22float2(*(__half2*)&a1.w); acc[6] = fmaf(w1, f.x, acc[6]); acc[7] = fmaf(w1, f.y, acc[7]);
    }

    if (d < N) {
        float dd = dinv[d];
        float w2 = dd * dd;
        uint4 a = *(const uint4*)(t + (size_t)d * 64 + p * 8);
        float4 b0 = *(const float4*)&bias[p * 8];
        float4 b1 = *(const float4*)&bias[p * 8 + 4];
        float2 s0 = __half22float2(*(__half2*)&a.x);
        float2 s1 = __half22float2(*(__half2*)&a.y);
        float2 s2 = __half22float2(*(__half2*)&a.z);
        float2 s3 = __half22float2(*(__half2*)&a.w);
        float o0 = fmaxf(fmaf(w2, s0.x, acc[0]) + b0.x, 0.f);
        float o1 = fmaxf(fmaf(w2, s0.y, acc[1]) + b0.y, 0.f);
        float o2 = fmaxf(fmaf(w2, s1.x, acc[2]) + b0.z, 0.f);
        float o3 = fmaxf(fmaf(w2, s1.y, acc[3]) + b0.w, 0.f);
        float o4 = fmaxf(fmaf(w2, s2.x, acc[4]) + b1.x, 0.f);
        float o5 = fmaxf(fmaf(w2, s2.y, acc[5]) + b1.y, 0.f);
        float o6 = fmaxf(fmaf(w2, s3.x, acc[6]) + b1.z, 0.f);
        float o7 = fmaxf(fmaf(w2, s3.y, acc[7]) + b1.w, 0.f);
        __half2 h0 = __floats2half2_rn(o0, o1);
        __half2 h1 = __floats2half2_rn(o2, o3);
        __half2 h2 = __floats2half2_rn(o4, o5);
        __half2 h3 = __floats2half2_rn(o6, o7);
        uint4 u = make_uint4(*(unsigned*)&h0, *(unsigned*)&h1,
                             *(unsigned*)&h2, *(unsigned*)&h3);
        *(uint4*)(agg + (size_t)d * 64 + p * 8) = u;
    }
}

extern "C" void kernel_launch(void* const* d_in, const int* in_sizes, int n_in,
                              void* d_out, int out_size, void* d_ws, size_t ws_size,
                              hipStream_t stream) {
    const float* x  = (const float*)d_in[0];
    const int*   ei = (const int*)d_in[1];
    const float* W1 = (const float*)d_in[2];
    const float* b1 = (const float*)d_in[3];
    const float* W2 = (const float*)d_in[4];
    const float* b2 = (const float*)d_in[5];
    const float* Wl = (const float*)d_in[6];
    const float* bl = (const float*)d_in[7];
    float*       out = (float*)d_out;

    const int N = in_sizes[0] / 64;
    const int E = in_sizes[1] / 2;
    const int* srcp = ei;
    const int* dstp = ei + E;

    const int NBC   = (N + BNODES - 1) / BNODES;             // buckets
    const int CH    = (((E + EBLKS - 1) / EBLKS) + 3) & ~3;  // chunk, mult of 4
    const int total = NBC * EBLKS;                           // offset matrix
    const int NBLK  = (total + 1023) / 1024;                 // scan blocks

    char*  ws  = (char*)d_ws;
    size_t off = 0;
    auto alloc = [&](size_t bytes) -> void* {
        void* p = (void*)(ws + off);
        off += (bytes + 255) & ~(size_t)255;
        return p;
    };
    int*    OFS     = (int*)alloc(((size_t)total + 1) * 4);
    int*    bsum    = (int*)alloc((size_t)NBLK * 4);
    int*    ebuf    = (int*)alloc((size_t)E * 4);
    int*    row_ptr = (int*)alloc((size_t)(N + 1) * 4);
    float*  dinv    = (float*)alloc((size_t)N * 4);
    int2*   colw    = (int2*)alloc((size_t)E * 8);
    __half* t       = (__half*)alloc((size_t)N * 64 * 2);
    __half* agg1    = (__half*)alloc((size_t)N * 64 * 2);
    __half* agg2    = agg1;   // safe: agg1 dead once mm2 wrote t

    const int nb_mm = (N + 63) / 64;
    const int nb_g  = (N + 31) / 32;

    // --- CSR build (no global atomics) ---
    k_p1hist   <<<EBLKS, TPB, 0, stream>>>(dstp, OFS, E, CH, NBC);
    k_scanA    <<<NBLK,  TPB, 0, stream>>>(OFS, bsum, total);
    k_scanB    <<<1,     TPB, 0, stream>>>(bsum, OFS, NBLK, total, E);
    k_scanC    <<<NBLK,  TPB, 0, stream>>>(OFS, bsum, total);
    k_p1scatter<<<EBLKS, TPB, 0, stream>>>(srcp, dstp, OFS, ebuf, E, CH, NBC);
    k_p2rowptr <<<NBC,   TPB, 0, stream>>>(ebuf, OFS, row_ptr, dinv, N, E, NBC);
    k_p2fill   <<<NBC,   TPB, 0, stream>>>(ebuf, OFS, row_ptr, dinv, colw, NBC);

    // --- layer 1 ---
    k_mm<64, false, false, true><<<nb_mm, 256, 0, stream>>>(x, W1, nullptr, t, N);
    k_gather<<<nb_g, 256, 0, stream>>>(row_ptr, colw, dinv, b1, t, agg1, N);

    // --- layer 2 ---
    k_mm<64, false, true, true><<<nb_mm, 256, 0, stream>>>(agg1, W2, nullptr, t, N);
    k_gather<<<nb_g, 256, 0, stream>>>(row_ptr, colw, dinv, b2, t, agg2, N);

    // --- head ---
    k_mm<32, true, true, false><<<nb_mm, 256, 0, stream>>>(agg2, Wl, bl, out, N);
}